// Round 7
// baseline (364.318 us; speedup 1.0000x reference)
//
#include <hip/hip_runtime.h>
#include <hip/hip_bf16.h>

typedef __bf16 v8bf __attribute__((ext_vector_type(8)));
typedef __bf16 v4bf __attribute__((ext_vector_type(4)));
typedef float  v4f  __attribute__((ext_vector_type(4)));

#define AS1 __attribute__((address_space(1)))
#define AS3 __attribute__((address_space(3)))

static __device__ __forceinline__ void gload_lds16(const void* g, void* l) {
  __builtin_amdgcn_global_load_lds((const AS1 void*)g, (AS3 void*)l, 16, 0, 0);
}

// ---- elementwise fp32 -> bf16 (n multiple of 4) ----
__global__ __launch_bounds__(256)
void cvt_bf16(const float* __restrict__ in, __bf16* __restrict__ out, long n) {
  const long i = ((long)blockIdx.x * 256 + threadIdx.x) * 4;
  if (i >= n) return;
  v4f v = *(const v4f*)&in[i];
  v4bf o;
#pragma unroll
  for (int u = 0; u < 4; ++u) o[u] = (__bf16)v[u];
  *(v4bf*)&out[i] = o;
}

// ---- zero fp32 buffer ----
__global__ __launch_bounds__(256)
void zero_f32(float* __restrict__ p, long n) {
  const long i = ((long)blockIdx.x * 256 + threadIdx.x) * 4;
  if (i >= n) return;
  *(v4f*)&p[i] = v4f{0.f, 0.f, 0.f, 0.f};
}

// ---- X [n][c][b] fp32 -> XT [n][b][c] bf16, 64x64 tiles via LDS ----
__global__ __launch_bounds__(256)
void cvt_transpose(const float* __restrict__ X, __bf16* __restrict__ XT) {
  __shared__ float t[64][65];
  const int b0 = blockIdx.x * 64, c0 = blockIdx.y * 64;
  const long n = blockIdx.z;
  const float* Xp = X + n * (1024L * 2048);
  __bf16* Tp = XT + n * (2048L * 1024);
  const int tid = threadIdx.x;
  const int r16 = tid >> 4, c4 = (tid & 15) * 4;
#pragma unroll
  for (int it = 0; it < 4; ++it) {
    const int r = r16 + it * 16;   // local c
    *(v4f*)&t[r][c4] = *(const v4f*)&Xp[(long)(c0 + r) * 2048 + b0 + c4];
  }
  __syncthreads();
  const int rb8 = tid >> 3, c8 = (tid & 7) * 8;
#pragma unroll
  for (int it = 0; it < 2; ++it) {
    const int rb = rb8 + it * 32;  // local b
    v8bf o;
#pragma unroll
    for (int u = 0; u < 8; ++u) o[u] = (__bf16)t[c8 + u][rb];
    *(v8bf*)&Tp[(long)(b0 + rb) * 1024 + c0 + c8] = o;
  }
}

// ---- 256x256 TN GEMM, 8-phase, m201 two-barrier bracketing ----
// 8 waves (4x2 qr/qc), BK=64, double-buffered LDS (128 KiB), XOR-swizzle
// (slot s of row r holds k-chunk s^(r&7); pre-swizzled global src, linear
// LDS dest; fr/q read pattern = MEASURED 0 bank conflicts).
// Phase = [issue ds_reads][issue stage][BAR][lgkmcnt(0)][setprio MFMA]
//         [vmcnt(6) at ph4/8][BAR]  -- reads stay in flight across the
// barrier so the LDS port drains while early waves run MFMA (the R3/R6
// drain-before-barrier bracketing serialized port vs MFMA).
// A fragments held in af0/af1 -> ph4/ph8 have no ds_reads (24/K-tile/wave).
// Stage/vmcnt ledger identical to R6 (WAR re-verified for 2-barrier).
// EPI 0: += bias[col], clamp +-32; fused rownorm -> dk2[row] (atomic)
// EPI 1: *= rsqrt(max(dk2[row]*dq2[col],eps)), clamp +-4, store exp();
//        fused row-sum of bf16(exp) -> snorm[row] (atomic)
// EPI 2: /= dq2[col] (softmax denominator), clamp +-1.
#define BAR __builtin_amdgcn_s_barrier()
#define LGKM0 do { asm volatile("s_waitcnt lgkmcnt(0)" ::: "memory"); \
                   __builtin_amdgcn_sched_barrier(0); } while (0)
#define LGKM8 do { asm volatile("s_waitcnt lgkmcnt(8)" ::: "memory"); \
                   __builtin_amdgcn_sched_barrier(0); } while (0)
#define VMW(N) do { asm volatile("s_waitcnt vmcnt(" #N ")" ::: "memory"); \
                    __builtin_amdgcn_sched_barrier(0); } while (0)
#define MM(AF, HM, HN) do { \
  __builtin_amdgcn_s_setprio(1); \
  _Pragma("unroll") for (int ks = 0; ks < 2; ++ks) \
  _Pragma("unroll") for (int u = 0; u < 2; ++u) \
  _Pragma("unroll") for (int j = 0; j < 4; ++j) \
    acc[2 * (HM) + u][4 * (HN) + j] = __builtin_amdgcn_mfma_f32_16x16x32_bf16( \
        bfr[j][ks], AF[u][ks], acc[2 * (HM) + u][4 * (HN) + j], 0, 0, 0); \
  __builtin_amdgcn_s_setprio(0); } while (0)

template<int KD, int EPI, typename OT>
__global__ __launch_bounds__(512, 2)
void gemm256(const __bf16* __restrict__ Abase, const __bf16* __restrict__ Bbase,
             OT* __restrict__ Obase, const __bf16* __restrict__ bias,
             float* __restrict__ dk2, const float* __restrict__ dq2,
             float* __restrict__ snorm,
             long sA, long sB, long sO) {
  // buf0 (even tiles): A[256][64] @0, B @16384; buf1 (odd tiles) @32768.
  __shared__ __align__(128) __bf16 lds[65536];

  const int tid = threadIdx.x;
  const int wave = tid >> 6, lane = tid & 63;
  const int qr = wave >> 1, qc = wave & 1;   // 4x2 wave grid
  const int fr = lane & 15, q = lane >> 4;
  const int f7 = fr & 7;

  // XCD-chunked bijective swizzle (nwg divisible by 8)
  const int gx = gridDim.x, gy = gridDim.y;
  int id = blockIdx.x + gx * (blockIdx.y + gy * blockIdx.z);
  const int chunk8 = (gx * gy * gridDim.z) >> 3;
  id = (id & 7) * chunk8 + (id >> 3);
  const int bx = id % gx;
  const int rem = id / gx;
  const int by = rem % gy;
  const long z = rem / gy;

  const int n0 = bx * 256, m0 = by * 256;
  const __bf16* A = Abase + z * sA + (long)m0 * KD;
  const __bf16* B = Bbase + z * sB + (long)n0 * KD;

  // staging: wave w, instr i covers rows [half*128+w*16+i*8, +8);
  // lane l -> row +(l>>3), slot (l&7) holds k-chunk ((l&7)^(l>>3)).
  const int lrow = wave * 16 + (lane >> 3);
  const int lchunk = ((lane & 7) ^ (lane >> 3)) << 3;
  const __bf16* Alane = A + (long)lrow * KD + lchunk;
  const __bf16* Blane = B + (long)lrow * KD + lchunk;
  const int dbase = wave * 1024;

  auto stage = [&](int kt, int isB, int half) {
    const __bf16* gp = (isB ? Blane : Alane) + (long)(half * 128) * KD + kt * 64;
    __bf16* dp = lds + (kt & 1) * 32768 + isB * 16384 + half * 8192 + dbase;
    gload_lds16(gp, dp);
    gload_lds16(gp + (long)8 * KD, dp + 512);
  };

  v4f acc[4][8];
#pragma unroll
  for (int i = 0; i < 4; ++i)
#pragma unroll
    for (int j = 0; j < 8; ++j) acc[i][j] = {0.f, 0.f, 0.f, 0.f};

  v8bf af0[2][2], af1[2][2], bfr[4][2];
  auto readA = [&](const __bf16* sa, int hm, v8bf (&dst)[2][2]) {
#pragma unroll
    for (int u = 0; u < 2; ++u) {
      const int rb = (hm * 128 + qr * 32 + u * 16 + fr) * 64;
      dst[u][0] = *(const v8bf*)&sa[rb + ((q ^ f7) << 3)];
      dst[u][1] = *(const v8bf*)&sa[rb + (((q | 4) ^ f7) << 3)];
    }
  };
  auto readB = [&](const __bf16* sb, int hn) {
#pragma unroll
    for (int j = 0; j < 4; ++j) {
      const int rb = (hn * 128 + qc * 64 + j * 16 + fr) * 64;
      bfr[j][0] = *(const v8bf*)&sb[rb + ((q ^ f7) << 3)];
      bfr[j][1] = *(const v8bf*)&sb[rb + (((q | 4) ^ f7) << 3)];
    }
  };

  constexpr int NT = KD / 64;
  constexpr int NI = NT / 2;
  __bf16* s0 = lds;
  __bf16* s1 = lds + 32768;

  // prologue: tile0 all 4 halves + tile1 {B0,A1,B1}; tile1.A0 is JIT at ph1.
  stage(0, 0, 0); stage(0, 1, 0); stage(0, 0, 1); stage(0, 1, 1);
  stage(1, 1, 0); stage(1, 0, 1); stage(1, 1, 1);
  VMW(6); BAR;

#pragma unroll 1
  for (int m = 0; m < NI; ++m) {
    const bool nl = (m != NI - 1);
    const int t1 = 2 * m + 1, t2 = 2 * m + 2, t3 = 2 * m + 3;
    // ph1: issue reads s0.A0->af0, s0.B-half0 ; stage s1.A0 (t1, JIT)
    readA(s0, 0, af0); readB(s0 + 16384, 0);
    stage(t1, 0, 0);
    LGKM8; BAR; LGKM0; MM(af0, 0, 0); BAR;
    // ph2: reads s0.A1 -> af1 (bfr held); stage s0.B0 (t2)
    readA(s0, 1, af1);
    if (nl) stage(t2, 1, 0);
    BAR; LGKM0; MM(af1, 1, 0); BAR;
    // ph3: reads s0.B-half1 (af1 held); stage s0.A1 (t2)
    readB(s0 + 16384, 1);
    if (nl) stage(t2, 0, 1);
    BAR; LGKM0; MM(af1, 1, 1); BAR;
    // ph4: NO ds_reads (af0, bfr held); stage s0.B1 (t2); vmcnt under MFMA
    if (nl) stage(t2, 1, 1);
    BAR; MM(af0, 0, 1);
    if (nl) { VMW(6); } else { VMW(0); }
    BAR;
    // ph5: reads s1.A0 -> af0, s1.B-half0 ; stage s0.A0 (t2)
    readA(s1, 0, af0); readB(s1 + 16384, 0);
    if (nl) stage(t2, 0, 0);
    LGKM8; BAR; LGKM0; MM(af0, 0, 0); BAR;
    // ph6: reads s1.A1 -> af1 ; stage s1.B0 (t3)
    readA(s1, 1, af1);
    if (nl) stage(t3, 1, 0);
    BAR; LGKM0; MM(af1, 1, 0); BAR;
    // ph7: reads s1.B-half1 ; stage s1.A1 (t3)
    readB(s1 + 16384, 1);
    if (nl) stage(t3, 0, 1);
    BAR; LGKM0; MM(af1, 1, 1); BAR;
    // ph8: NO ds_reads ; stage s1.B1 (t3); vmcnt under MFMA
    if (nl) stage(t3, 1, 1);
    BAR; MM(af0, 0, 1);
    if (nl) { VMW(6); } else { VMW(0); }
    BAR;
  }

  // Epilogue. acc[ai][bj] reg r:
  //   row = m0 + (ai>>1)*128 + qr*32 + (ai&1)*16 + fr
  //   col = n0 + (bj>>2)*128 + qc*64 + (bj&3)*16 + q*4 + r  (r contiguous)
  OT* O = Obase + z * sO;
  const int ldo = gx * 256;
#pragma unroll
  for (int ai = 0; ai < 4; ++ai) {
    const int row = m0 + (ai >> 1) * 128 + qr * 32 + (ai & 1) * 16 + fr;
    float rk = 0.f, rs = 0.f;
    if (EPI == 1) rk = dk2[z * 2048 + row];
#pragma unroll
    for (int bj = 0; bj < 8; ++bj) {
      const int colb = n0 + (bj >> 2) * 128 + qc * 64 + (bj & 3) * 16 + q * 4;
      float cv[4];
      if (EPI == 0) {
        v4bf bb = *(const v4bf*)&bias[colb];
#pragma unroll
        for (int r = 0; r < 4; ++r) cv[r] = (float)bb[r];
      }
      if (EPI == 1 || EPI == 2) {
        v4f dd = *(const v4f*)&dq2[z * 2048 + colb];
#pragma unroll
        for (int r = 0; r < 4; ++r) cv[r] = dd[r];
      }
      float vv[4];
#pragma unroll
      for (int r = 0; r < 4; ++r) {
        float v = acc[ai][bj][r];
        if (EPI == 0) {
          v = fminf(fmaxf(v + cv[r], -32.f), 32.f);
          rs += v * v;
        }
        if (EPI == 1) {
          v *= rsqrtf(fmaxf(rk * cv[r], 1e-12f));
          v = fminf(fmaxf(v, -4.f), 4.f);
          v = __expf(v);
        }
        if (EPI == 2) {
          v = v / cv[r];
          v = fminf(fmaxf(v, -1.f), 1.f);
        }
        vv[r] = v;
      }
      if (sizeof(OT) == 2) {
        v4bf o;
#pragma unroll
        for (int r = 0; r < 4; ++r) o[r] = (__bf16)vv[r];
        if (EPI == 1) {
#pragma unroll
          for (int r = 0; r < 4; ++r) rs += (float)o[r];  // denom = sum of stored bf16
        }
        *(v4bf*)&O[(long)row * ldo + colb] = o;
      } else {
        v4f o;
#pragma unroll
        for (int r = 0; r < 4; ++r) o[r] = vv[r];
        *(v4f*)&O[(long)row * ldo + colb] = o;
      }
    }
    if (EPI == 0) {
      rs += __shfl_xor(rs, 16);
      rs += __shfl_xor(rs, 32);
      if (q == 0) atomicAdd(&dk2[z * 2048 + row], rs);
    }
    if (EPI == 1) {
      rs += __shfl_xor(rs, 16);
      rs += __shfl_xor(rs, 32);
      if (q == 0) atomicAdd(&snorm[z * 2048 + row], rs);
    }
  }
}

extern "C" void kernel_launch(void* const* d_in, const int* in_sizes, int n_in,
                              void* d_out, int out_size, void* d_ws, size_t ws_size,
                              hipStream_t stream) {
  const float* X    = (const float*)d_in[0];
  const float* Wk_w = (const float*)d_in[1];
  const float* Wk_b = (const float*)d_in[2];
  const float* Wq_w = (const float*)d_in[3];
  const float* Wq_b = (const float*)d_in[4];
  float* out = (float*)d_out;

  // ws: [0,32M): XT bf16 [n][b][c] -> later Xbf bf16 [n][c][b]
  //     [32M,96M): YT bf16 [n][k][b] (holds E=exp after GEMM-Y)
  //     [96M+): DK2, DQ2, SNORM, Wk_bf, Wq_bf, bk_bf, bq_bf
  char* ws = (char*)d_ws;
  __bf16* XT  = (__bf16*)(ws);
  __bf16* Xbf = (__bf16*)(ws);
  __bf16* YT  = (__bf16*)(ws + 33554432L);
  char* aux   = ws + 100663296L;
  float*  DK2   = (float*)(aux);
  float*  DQ2   = (float*)(aux + 65536L);
  float*  SNORM = (float*)(aux + 131072L);
  __bf16* Wk_bf = (__bf16*)(aux + 196608L);
  __bf16* Wq_bf = (__bf16*)(aux + 196608L + 2097152L);
  __bf16* bk_bf = (__bf16*)(aux + 196608L + 4194304L);
  __bf16* bq_bf = (__bf16*)(aux + 196608L + 4196352L);
  // d_out (64 MiB) holds KT|QT until GEMM3 overwrites it with Z.
  __bf16* KT = (__bf16*)d_out;
  __bf16* QT = (__bf16*)((char*)d_out + 33554432L);

  // 0) convert weights/biases to bf16; zero DK2|DQ2|SNORM (contiguous 192 KiB)
  cvt_bf16<<<1024, 256, 0, stream>>>(Wk_w, Wk_bf, 1048576L);
  cvt_bf16<<<1024, 256, 0, stream>>>(Wq_w, Wq_bf, 1048576L);
  cvt_bf16<<<1, 256, 0, stream>>>(Wk_b, bk_bf, 1024L);
  cvt_bf16<<<1, 256, 0, stream>>>(Wq_b, bq_bf, 1024L);
  zero_f32<<<48, 256, 0, stream>>>(DK2, 49152L);
  // 1) XT[n][b][c] = (bf16) X[n][c][b]
  cvt_transpose<<<dim3(32, 16, 8), 256, 0, stream>>>(X, XT);
  // 2) KT[n][b][o] = XT[b,:]·Wk[o,:] + bk[o]; fused rownorm -> DK2; same for Q
  gemm256<1024, 0, __bf16><<<dim3(4, 8, 8), 512, 0, stream>>>(
      XT, Wk_bf, KT, bk_bf, DK2, nullptr, nullptr, 2048L * 1024, 0L, 2048L * 1024);
  gemm256<1024, 0, __bf16><<<dim3(4, 8, 8), 512, 0, stream>>>(
      XT, Wq_bf, QT, bq_bf, DQ2, nullptr, nullptr, 2048L * 1024, 0L, 2048L * 1024);
  // 3) Xbf = (bf16) X  (XT dead; same ws region)
  cvt_bf16<<<16384, 256, 0, stream>>>(X, Xbf, 16777216L);
  // 4) YT[n][k][b] = exp(clamp(cosine-score)); fused row-sum -> SNORM[n][k]
  gemm256<1024, 1, __bf16><<<dim3(8, 8, 8), 512, 0, stream>>>(
      KT, QT, YT, nullptr, DK2, DQ2, SNORM, 2048L * 1024, 2048L * 1024,
      2048L * 2048);
  // 5) Z[n][c][k] = (Xbf[c,:]·E[k,:]) / SNORM[k]  -> d_out fp32
  gemm256<2048, 2, float><<<dim3(8, 4, 8), 512, 0, stream>>>(
      Xbf, YT, out, nullptr, nullptr, SNORM, nullptr, 1024L * 2048,
      2048L * 2048, 1024L * 2048);
}

// Round 8
// 348.223 us; speedup vs baseline: 1.0462x; 1.0462x over previous
//
#include <hip/hip_runtime.h>
#include <hip/hip_bf16.h>

typedef __bf16 v8bf __attribute__((ext_vector_type(8)));
typedef __bf16 v4bf __attribute__((ext_vector_type(4)));
typedef float  v4f  __attribute__((ext_vector_type(4)));

#define AS1 __attribute__((address_space(1)))
#define AS3 __attribute__((address_space(3)))

static __device__ __forceinline__ void gload_lds16(const void* g, void* l) {
  __builtin_amdgcn_global_load_lds((const AS1 void*)g, (AS3 void*)l, 16, 0, 0);
}

// ---- elementwise fp32 -> bf16 (n multiple of 4) ----
__global__ __launch_bounds__(256)
void cvt_bf16(const float* __restrict__ in, __bf16* __restrict__ out, long n) {
  const long i = ((long)blockIdx.x * 256 + threadIdx.x) * 4;
  if (i >= n) return;
  v4f v = *(const v4f*)&in[i];
  v4bf o;
#pragma unroll
  for (int u = 0; u < 4; ++u) o[u] = (__bf16)v[u];
  *(v4bf*)&out[i] = o;
}

// ---- zero fp32 buffer ----
__global__ __launch_bounds__(256)
void zero_f32(float* __restrict__ p, long n) {
  const long i = ((long)blockIdx.x * 256 + threadIdx.x) * 4;
  if (i >= n) return;
  *(v4f*)&p[i] = v4f{0.f, 0.f, 0.f, 0.f};
}

// ---- X [n][c][b] fp32 -> XT [n][b][c] bf16, 64x64 tiles via LDS ----
__global__ __launch_bounds__(256)
void cvt_transpose(const float* __restrict__ X, __bf16* __restrict__ XT) {
  __shared__ float t[64][65];
  const int b0 = blockIdx.x * 64, c0 = blockIdx.y * 64;
  const long n = blockIdx.z;
  const float* Xp = X + n * (1024L * 2048);
  __bf16* Tp = XT + n * (2048L * 1024);
  const int tid = threadIdx.x;
  const int r16 = tid >> 4, c4 = (tid & 15) * 4;
#pragma unroll
  for (int it = 0; it < 4; ++it) {
    const int r = r16 + it * 16;   // local c
    *(v4f*)&t[r][c4] = *(const v4f*)&Xp[(long)(c0 + r) * 2048 + b0 + c4];
  }
  __syncthreads();
  const int rb8 = tid >> 3, c8 = (tid & 7) * 8;
#pragma unroll
  for (int it = 0; it < 2; ++it) {
    const int rb = rb8 + it * 32;  // local b
    v8bf o;
#pragma unroll
    for (int u = 0; u < 8; ++u) o[u] = (__bf16)t[c8 + u][rb];
    *(v8bf*)&Tp[(long)(b0 + rb) * 1024 + c0 + c8] = o;
  }
}

// ---- 256x256 TN GEMM, 8-phase (R6-verified core), counted vmcnt ----
// 8 waves (4x2 qr/qc), BK=64, double-buffered LDS (128 KiB), XOR-swizzle
// (slot s of row r holds k-chunk s^(r&7); pre-swizzled global src, linear
// LDS dest; fr/q fragment read pattern = MEASURED 0 bank conflicts).
// Phase = [ds_reads][stage][lgkmcnt(0)][vmcnt(6) at ph4/8][BAR][setprio MFMA]
// A fragments held in af0/af1 across phases -> ph4/ph8 have no ds_reads
// (24 ds_read_b128 per K-tile/wave).
// Swapped mfma(B,A): acc reg-quad = 4 consecutive cols -> vector stores.
// EPI 0 (merged K/Q projection): B is combined W[2048][1024]; block's col
//   tile is entirely in K half (n0<1024 -> out KT, norm dk2) or Q half
//   (-> out Obase2/QT, norm dk2b). += bias[global col], clamp +-32; fused
//   rownorm (atomic).
// EPI 1: *= rsqrt(max(dk2[row]*dq2[col],eps)), clamp +-4, store exp();
//        fused row-sum of bf16(exp) -> snorm[row] (atomic)
// EPI 2: /= dq2[col] (softmax denominator), clamp +-1.
#define BAR __builtin_amdgcn_s_barrier()
#define LGKM0 do { asm volatile("s_waitcnt lgkmcnt(0)" ::: "memory"); \
                   __builtin_amdgcn_sched_barrier(0); } while (0)
#define VMW(N) do { asm volatile("s_waitcnt vmcnt(" #N ")" ::: "memory"); \
                    __builtin_amdgcn_sched_barrier(0); } while (0)
#define MM(AF, HM, HN) do { \
  __builtin_amdgcn_s_setprio(1); \
  _Pragma("unroll") for (int ks = 0; ks < 2; ++ks) \
  _Pragma("unroll") for (int u = 0; u < 2; ++u) \
  _Pragma("unroll") for (int j = 0; j < 4; ++j) \
    acc[2 * (HM) + u][4 * (HN) + j] = __builtin_amdgcn_mfma_f32_16x16x32_bf16( \
        bfr[j][ks], AF[u][ks], acc[2 * (HM) + u][4 * (HN) + j], 0, 0, 0); \
  __builtin_amdgcn_s_setprio(0); } while (0)

template<int KD, int EPI, typename OT>
__global__ __launch_bounds__(512, 2)
void gemm256(const __bf16* __restrict__ Abase, const __bf16* __restrict__ Bbase,
             OT* __restrict__ Obase, OT* __restrict__ Obase2,
             const __bf16* __restrict__ bias,
             float* __restrict__ dk2, float* __restrict__ dk2b,
             const float* __restrict__ dq2, float* __restrict__ snorm,
             long sA, long sB, long sO, int ldo) {
  // buf0 (even tiles): A[256][64] @0, B @16384; buf1 (odd tiles) @32768.
  __shared__ __align__(128) __bf16 lds[65536];

  const int tid = threadIdx.x;
  const int wave = tid >> 6, lane = tid & 63;
  const int qr = wave >> 1, qc = wave & 1;   // 4x2 wave grid
  const int fr = lane & 15, q = lane >> 4;
  const int f7 = fr & 7;

  // XCD-chunked bijective swizzle (nwg divisible by 8)
  const int gx = gridDim.x, gy = gridDim.y;
  int id = blockIdx.x + gx * (blockIdx.y + gy * blockIdx.z);
  const int chunk8 = (gx * gy * gridDim.z) >> 3;
  id = (id & 7) * chunk8 + (id >> 3);
  const int bx = id % gx;
  const int rem = id / gx;
  const int by = rem % gy;
  const long z = rem / gy;

  const int n0 = bx * 256, m0 = by * 256;
  const __bf16* A = Abase + z * sA + (long)m0 * KD;
  const __bf16* B = Bbase + z * sB + (long)n0 * KD;

  // staging: wave w, instr i covers rows [half*128+w*16+i*8, +8);
  // lane l -> row +(l>>3), slot (l&7) holds k-chunk ((l&7)^(l>>3)).
  const int lrow = wave * 16 + (lane >> 3);
  const int lchunk = ((lane & 7) ^ (lane >> 3)) << 3;
  const __bf16* Alane = A + (long)lrow * KD + lchunk;
  const __bf16* Blane = B + (long)lrow * KD + lchunk;
  const int dbase = wave * 1024;

  auto stage = [&](int kt, int isB, int half) {
    const __bf16* gp = (isB ? Blane : Alane) + (long)(half * 128) * KD + kt * 64;
    __bf16* dp = lds + (kt & 1) * 32768 + isB * 16384 + half * 8192 + dbase;
    gload_lds16(gp, dp);
    gload_lds16(gp + (long)8 * KD, dp + 512);
  };

  v4f acc[4][8];
#pragma unroll
  for (int i = 0; i < 4; ++i)
#pragma unroll
    for (int j = 0; j < 8; ++j) acc[i][j] = {0.f, 0.f, 0.f, 0.f};

  v8bf af0[2][2], af1[2][2], bfr[4][2];
  auto readA = [&](const __bf16* sa, int hm, v8bf (&dst)[2][2]) {
#pragma unroll
    for (int u = 0; u < 2; ++u) {
      const int rb = (hm * 128 + qr * 32 + u * 16 + fr) * 64;
      dst[u][0] = *(const v8bf*)&sa[rb + ((q ^ f7) << 3)];
      dst[u][1] = *(const v8bf*)&sa[rb + (((q | 4) ^ f7) << 3)];
    }
  };
  auto readB = [&](const __bf16* sb, int hn) {
#pragma unroll
    for (int j = 0; j < 4; ++j) {
      const int rb = (hn * 128 + qc * 64 + j * 16 + fr) * 64;
      bfr[j][0] = *(const v8bf*)&sb[rb + ((q ^ f7) << 3)];
      bfr[j][1] = *(const v8bf*)&sb[rb + (((q | 4) ^ f7) << 3)];
    }
  };

  constexpr int NT = KD / 64;
  constexpr int NI = NT / 2;
  __bf16* s0 = lds;
  __bf16* s1 = lds + 32768;

  // prologue: tile0 all 4 halves + tile1 {B0,A1,B1}; tile1.A0 is JIT at ph1.
  stage(0, 0, 0); stage(0, 1, 0); stage(0, 0, 1); stage(0, 1, 1);
  stage(1, 1, 0); stage(1, 0, 1); stage(1, 1, 1);
  VMW(6); BAR;

#pragma unroll 1
  for (int m = 0; m < NI; ++m) {
    const bool nl = (m != NI - 1);
    const int t1 = 2 * m + 1, t2 = 2 * m + 2, t3 = 2 * m + 3;
    // ph1: reads s0.A0 -> af0, s0.B-half0 ; stage s1.A0 (t1, JIT)
    readA(s0, 0, af0); readB(s0 + 16384, 0);
    stage(t1, 0, 0);
    LGKM0; BAR; MM(af0, 0, 0);
    // ph2: reads s0.A1 -> af1 (bfr held); stage s0.B0 (t2)
    readA(s0, 1, af1);
    if (nl) stage(t2, 1, 0);
    LGKM0; BAR; MM(af1, 1, 0);
    // ph3: reads s0.B-half1 (af1 held); stage s0.A1 (t2)
    readB(s0 + 16384, 1);
    if (nl) stage(t2, 0, 1);
    LGKM0; BAR; MM(af1, 1, 1);
    // ph4: NO ds_reads (af0, bfr held); stage s0.B1 (t2); counted vmcnt
    if (nl) stage(t2, 1, 1);
    if (nl) { VMW(6); } else { VMW(0); }
    BAR; MM(af0, 0, 1);
    // ph5: reads s1.A0 -> af0, s1.B-half0 ; stage s0.A0 (t2)
    readA(s1, 0, af0); readB(s1 + 16384, 0);
    if (nl) stage(t2, 0, 0);
    LGKM0; BAR; MM(af0, 0, 0);
    // ph6: reads s1.A1 -> af1 ; stage s1.B0 (t3)
    readA(s1, 1, af1);
    if (nl) stage(t3, 1, 0);
    LGKM0; BAR; MM(af1, 1, 0);
    // ph7: reads s1.B-half1 ; stage s1.A1 (t3)
    readB(s1 + 16384, 1);
    if (nl) stage(t3, 0, 1);
    LGKM0; BAR; MM(af1, 1, 1);
    // ph8: NO ds_reads ; stage s1.B1 (t3); counted vmcnt
    if (nl) stage(t3, 1, 1);
    if (nl) { VMW(6); } else { VMW(0); }
    BAR; MM(af0, 0, 1);
  }

  // Output routing (EPI 0 merged K/Q): this block's 256 cols are entirely
  // in one half; pick output base, norm target, and column offset.
  OT* Ob = Obase;
  float* dkp = dk2;
  int coff = 0;
  if (EPI == 0 && n0 >= 1024) { Ob = Obase2; dkp = dk2b; coff = 1024; }
  OT* O = Ob + z * sO;

  // Epilogue. acc[ai][bj] reg r:
  //   row = m0 + (ai>>1)*128 + qr*32 + (ai&1)*16 + fr
  //   col = n0 + (bj>>2)*128 + qc*64 + (bj&3)*16 + q*4 + r  (r contiguous)
#pragma unroll
  for (int ai = 0; ai < 4; ++ai) {
    const int row = m0 + (ai >> 1) * 128 + qr * 32 + (ai & 1) * 16 + fr;
    float rk = 0.f, rs = 0.f;
    if (EPI == 1) rk = dk2[z * 2048 + row];
#pragma unroll
    for (int bj = 0; bj < 8; ++bj) {
      const int colb = n0 + (bj >> 2) * 128 + qc * 64 + (bj & 3) * 16 + q * 4;
      float cv[4];
      if (EPI == 0) {
        v4bf bb = *(const v4bf*)&bias[colb];
#pragma unroll
        for (int r = 0; r < 4; ++r) cv[r] = (float)bb[r];
      }
      if (EPI == 1 || EPI == 2) {
        v4f dd = *(const v4f*)&dq2[z * 2048 + colb];
#pragma unroll
        for (int r = 0; r < 4; ++r) cv[r] = dd[r];
      }
      float vv[4];
#pragma unroll
      for (int r = 0; r < 4; ++r) {
        float v = acc[ai][bj][r];
        if (EPI == 0) {
          v = fminf(fmaxf(v + cv[r], -32.f), 32.f);
          rs += v * v;
        }
        if (EPI == 1) {
          v *= rsqrtf(fmaxf(rk * cv[r], 1e-12f));
          v = fminf(fmaxf(v, -4.f), 4.f);
          v = __expf(v);
        }
        if (EPI == 2) {
          v = v / cv[r];
          v = fminf(fmaxf(v, -1.f), 1.f);
        }
        vv[r] = v;
      }
      if (sizeof(OT) == 2) {
        v4bf o;
#pragma unroll
        for (int r = 0; r < 4; ++r) o[r] = (__bf16)vv[r];
        if (EPI == 1) {
#pragma unroll
          for (int r = 0; r < 4; ++r) rs += (float)o[r];  // denom = sum of stored bf16
        }
        *(v4bf*)&O[(long)row * ldo + (colb - coff)] = o;
      } else {
        v4f o;
#pragma unroll
        for (int r = 0; r < 4; ++r) o[r] = vv[r];
        *(v4f*)&O[(long)row * ldo + (colb - coff)] = o;
      }
    }
    if (EPI == 0) {
      rs += __shfl_xor(rs, 16);
      rs += __shfl_xor(rs, 32);
      if (q == 0) atomicAdd(&dkp[z * 2048 + row], rs);
    }
    if (EPI == 1) {
      rs += __shfl_xor(rs, 16);
      rs += __shfl_xor(rs, 32);
      if (q == 0) atomicAdd(&snorm[z * 2048 + row], rs);
    }
  }
}

extern "C" void kernel_launch(void* const* d_in, const int* in_sizes, int n_in,
                              void* d_out, int out_size, void* d_ws, size_t ws_size,
                              hipStream_t stream) {
  const float* X    = (const float*)d_in[0];
  const float* Wk_w = (const float*)d_in[1];
  const float* Wk_b = (const float*)d_in[2];
  const float* Wq_w = (const float*)d_in[3];
  const float* Wq_b = (const float*)d_in[4];
  float* out = (float*)d_out;

  // ws: [0,32M): XT bf16 [n][b][c] -> later Xbf bf16 [n][c][b]
  //     [32M,96M): YT bf16 [n][k][b] (holds E=exp after GEMM-Y)
  //     [96M+): DK2, DQ2, SNORM, W (combined [2048][1024]), bb (combined bias)
  char* ws = (char*)d_ws;
  __bf16* XT  = (__bf16*)(ws);
  __bf16* Xbf = (__bf16*)(ws);
  __bf16* YT  = (__bf16*)(ws + 33554432L);
  char* aux   = ws + 100663296L;
  float*  DK2   = (float*)(aux);
  float*  DQ2   = (float*)(aux + 65536L);
  float*  SNORM = (float*)(aux + 131072L);
  __bf16* W     = (__bf16*)(aux + 196608L);               // 4 MiB
  __bf16* bb    = (__bf16*)(aux + 196608L + 4194304L);    // 4 KiB
  // d_out (64 MiB) holds KT|QT until GEMM3 overwrites it with Z.
  __bf16* KT = (__bf16*)d_out;
  __bf16* QT = (__bf16*)((char*)d_out + 33554432L);

  // 0) convert weights/biases into combined W[2048][1024] / bb[2048];
  //    zero DK2|DQ2|SNORM (contiguous 192 KiB)
  cvt_bf16<<<1024, 256, 0, stream>>>(Wk_w, W, 1048576L);
  cvt_bf16<<<1024, 256, 0, stream>>>(Wq_w, W + 1048576L, 1048576L);
  cvt_bf16<<<1, 256, 0, stream>>>(Wk_b, bb, 1024L);
  cvt_bf16<<<1, 256, 0, stream>>>(Wq_b, bb + 1024L, 1024L);
  zero_f32<<<48, 256, 0, stream>>>(DK2, 49152L);
  // 1) XT[n][b][c] = (bf16) X[n][c][b]
  cvt_transpose<<<dim3(32, 16, 8), 256, 0, stream>>>(X, XT);
  // 2) merged projection: [KT|QT][n][b][o] = XT[b,:]·W[o,:] + bb[o];
  //    fused rownorms -> DK2 (K half), DQ2 (Q half)
  gemm256<1024, 0, __bf16><<<dim3(8, 8, 8), 512, 0, stream>>>(
      XT, W, KT, QT, bb, DK2, DQ2, nullptr, nullptr,
      2048L * 1024, 0L, 2048L * 1024, 1024);
  // 3) Xbf = (bf16) X  (XT dead; same ws region)
  cvt_bf16<<<16384, 256, 0, stream>>>(X, Xbf, 16777216L);
  // 4) YT[n][k][b] = exp(clamp(cosine-score)); fused row-sum -> SNORM[n][k]
  gemm256<1024, 1, __bf16><<<dim3(8, 8, 8), 512, 0, stream>>>(
      KT, QT, YT, nullptr, nullptr, DK2, nullptr, DQ2, SNORM,
      2048L * 1024, 2048L * 1024, 2048L * 2048, 2048);
  // 5) Z[n][c][k] = (Xbf[c,:]·E[k,:]) / SNORM[k]  -> d_out fp32
  gemm256<2048, 2, float><<<dim3(8, 4, 8), 512, 0, stream>>>(
      Xbf, YT, out, nullptr, nullptr, nullptr, nullptr, SNORM, nullptr,
      1024L * 2048, 2048L * 2048, 1024L * 2048, 2048);
}

// Round 11
// 347.278 us; speedup vs baseline: 1.0491x; 1.0027x over previous
//
#include <hip/hip_runtime.h>
#include <hip/hip_bf16.h>

typedef __bf16 v8bf __attribute__((ext_vector_type(8)));
typedef __bf16 v4bf __attribute__((ext_vector_type(4)));
typedef float  v4f  __attribute__((ext_vector_type(4)));

#define AS1 __attribute__((address_space(1)))
#define AS3 __attribute__((address_space(3)))

static __device__ __forceinline__ void gload_lds16(const void* g, void* l) {
  __builtin_amdgcn_global_load_lds((const AS1 void*)g, (AS3 void*)l, 16, 0, 0);
}

// ---- elementwise fp32 -> bf16 (n multiple of 4) ----
__global__ __launch_bounds__(256)
void cvt_bf16(const float* __restrict__ in, __bf16* __restrict__ out, long n) {
  const long i = ((long)blockIdx.x * 256 + threadIdx.x) * 4;
  if (i >= n) return;
  v4f v = *(const v4f*)&in[i];
  v4bf o;
#pragma unroll
  for (int u = 0; u < 4; ++u) o[u] = (__bf16)v[u];
  *(v4bf*)&out[i] = o;
}

// ---- combined Wk|Wq fp32 -> bf16 into W[2048][1024] (one dispatch) ----
__global__ __launch_bounds__(256)
void cvt_weights(const float* __restrict__ wk, const float* __restrict__ wq,
                 __bf16* __restrict__ W) {
  const float* src = blockIdx.y ? wq : wk;
  __bf16* dst = W + (long)blockIdx.y * 1048576L;
  const long i = ((long)blockIdx.x * 256 + threadIdx.x) * 4;
  v4f v = *(const v4f*)&src[i];
  v4bf o;
#pragma unroll
  for (int u = 0; u < 4; ++u) o[u] = (__bf16)v[u];
  *(v4bf*)&dst[i] = o;
}

// ---- biases -> bf16 + zero DK2|DQ2|SNORM, single block ----
__global__ __launch_bounds__(256)
void prep_small(const float* __restrict__ bk, const float* __restrict__ bq,
                __bf16* __restrict__ bb, float* __restrict__ zbuf) {
  const int tid = threadIdx.x;
  {
    v4f v = *(const v4f*)&bk[tid * 4];
    v4bf o;
#pragma unroll
    for (int u = 0; u < 4; ++u) o[u] = (__bf16)v[u];
    *(v4bf*)&bb[tid * 4] = o;
    v = *(const v4f*)&bq[tid * 4];
#pragma unroll
    for (int u = 0; u < 4; ++u) o[u] = (__bf16)v[u];
    *(v4bf*)&bb[1024 + tid * 4] = o;
  }
  // zero 49152 floats (DK2|DQ2|SNORM): 48 v4f per thread
#pragma unroll
  for (int it = 0; it < 48; ++it)
    *(v4f*)&zbuf[(it * 256 + tid) * 4] = v4f{0.f, 0.f, 0.f, 0.f};
}

// ---- X [n][c][b] fp32 -> XT [n][b][c] bf16, 64x64 tiles via LDS ----
__global__ __launch_bounds__(256)
void cvt_transpose(const float* __restrict__ X, __bf16* __restrict__ XT) {
  __shared__ float t[64][65];
  const int b0 = blockIdx.x * 64, c0 = blockIdx.y * 64;
  const long n = blockIdx.z;
  const float* Xp = X + n * (1024L * 2048);
  __bf16* Tp = XT + n * (2048L * 1024);
  const int tid = threadIdx.x;
  const int r16 = tid >> 4, c4 = (tid & 15) * 4;
#pragma unroll
  for (int it = 0; it < 4; ++it) {
    const int r = r16 + it * 16;   // local c
    *(v4f*)&t[r][c4] = *(const v4f*)&Xp[(long)(c0 + r) * 2048 + b0 + c4];
  }
  __syncthreads();
  const int rb8 = tid >> 3, c8 = (tid & 7) * 8;
#pragma unroll
  for (int it = 0; it < 2; ++it) {
    const int rb = rb8 + it * 32;  // local b
    v8bf o;
#pragma unroll
    for (int u = 0; u < 8; ++u) o[u] = (__bf16)t[c8 + u][rb];
    *(v8bf*)&Tp[(long)(b0 + rb) * 1024 + c0 + c8] = o;
  }
}

// ---- 256x256 TN GEMM, 8-phase (R6/R8-verified core), counted vmcnt ----
// 8 waves (4x2 qr/qc), BK=64, double-buffered LDS (128 KiB), XOR-swizzle
// (slot s of row r holds k-chunk s^(r&7); pre-swizzled global src, linear
// LDS dest; fr/q fragment read pattern = MEASURED 0 bank conflicts).
// Phase = [ds_reads][stage][lgkmcnt(0)][vmcnt(6) at ph4/8][BAR][setprio MFMA]
// A fragments held in af0/af1 across phases -> ph4/ph8 have no ds_reads
// (24 ds_read_b128 per K-tile/wave).
// Swapped mfma(B,A): acc reg-quad = 4 consecutive cols -> vector stores.
// EPI 0 (merged K/Q projection): B = combined W[2048][1024]; col tile is
//   entirely in K half (-> KT, dk2) or Q half (-> QT, dk2b). += bias,
//   clamp +-32; fused rownorm (atomic).
// EPI 1: *= rsqrt(max(dk2[row]*dq2[col],eps)), clamp +-4, store exp();
//        fused row-sum of bf16(exp) -> snorm[row] (atomic)
// EPI 2: /= dq2[col] (softmax denominator), clamp +-1.
#define BAR __builtin_amdgcn_s_barrier()
#define LGKM0 do { asm volatile("s_waitcnt lgkmcnt(0)" ::: "memory"); \
                   __builtin_amdgcn_sched_barrier(0); } while (0)
#define VMW(N) do { asm volatile("s_waitcnt vmcnt(" #N ")" ::: "memory"); \
                    __builtin_amdgcn_sched_barrier(0); } while (0)
#define MM(AF, HM, HN) do { \
  __builtin_amdgcn_s_setprio(1); \
  _Pragma("unroll") for (int ks = 0; ks < 2; ++ks) \
  _Pragma("unroll") for (int u = 0; u < 2; ++u) \
  _Pragma("unroll") for (int j = 0; j < 4; ++j) \
    acc[2 * (HM) + u][4 * (HN) + j] = __builtin_amdgcn_mfma_f32_16x16x32_bf16( \
        bfr[j][ks], AF[u][ks], acc[2 * (HM) + u][4 * (HN) + j], 0, 0, 0); \
  __builtin_amdgcn_s_setprio(0); } while (0)

template<int KD, int EPI, typename OT>
__global__ __launch_bounds__(512, 2)
void gemm256(const __bf16* __restrict__ Abase, const __bf16* __restrict__ Bbase,
             OT* __restrict__ Obase, OT* __restrict__ Obase2,
             const __bf16* __restrict__ bias,
             float* __restrict__ dk2, float* __restrict__ dk2b,
             const float* __restrict__ dq2, float* __restrict__ snorm,
             long sA, long sB, long sO, int ldo) {
  // buf0 (even tiles): A[256][64] @0, B @16384; buf1 (odd tiles) @32768.
  __shared__ __align__(128) __bf16 lds[65536];

  const int tid = threadIdx.x;
  const int wave = tid >> 6, lane = tid & 63;
  const int qr = wave >> 1, qc = wave & 1;   // 4x2 wave grid
  const int fr = lane & 15, q = lane >> 4;
  const int f7 = fr & 7;

  // XCD-chunked bijective swizzle (nwg divisible by 8)
  const int gx = gridDim.x, gy = gridDim.y;
  int id = blockIdx.x + gx * (blockIdx.y + gy * blockIdx.z);
  const int chunk8 = (gx * gy * gridDim.z) >> 3;
  id = (id & 7) * chunk8 + (id >> 3);
  const int bx = id % gx;
  const int rem = id / gx;
  const int by = rem % gy;
  const long z = rem / gy;

  const int n0 = bx * 256, m0 = by * 256;
  const __bf16* A = Abase + z * sA + (long)m0 * KD;
  const __bf16* B = Bbase + z * sB + (long)n0 * KD;

  // staging: wave w, instr i covers rows [half*128+w*16+i*8, +8);
  // lane l -> row +(l>>3), slot (l&7) holds k-chunk ((l&7)^(l>>3)).
  const int lrow = wave * 16 + (lane >> 3);
  const int lchunk = ((lane & 7) ^ (lane >> 3)) << 3;
  const __bf16* Alane = A + (long)lrow * KD + lchunk;
  const __bf16* Blane = B + (long)lrow * KD + lchunk;
  const int dbase = wave * 1024;

  auto stage = [&](int kt, int isB, int half) {
    const __bf16* gp = (isB ? Blane : Alane) + (long)(half * 128) * KD + kt * 64;
    __bf16* dp = lds + (kt & 1) * 32768 + isB * 16384 + half * 8192 + dbase;
    gload_lds16(gp, dp);
    gload_lds16(gp + (long)8 * KD, dp + 512);
  };

  v4f acc[4][8];
#pragma unroll
  for (int i = 0; i < 4; ++i)
#pragma unroll
    for (int j = 0; j < 8; ++j) acc[i][j] = {0.f, 0.f, 0.f, 0.f};

  v8bf af0[2][2], af1[2][2], bfr[4][2];
  auto readA = [&](const __bf16* sa, int hm, v8bf (&dst)[2][2]) {
#pragma unroll
    for (int u = 0; u < 2; ++u) {
      const int rb = (hm * 128 + qr * 32 + u * 16 + fr) * 64;
      dst[u][0] = *(const v8bf*)&sa[rb + ((q ^ f7) << 3)];
      dst[u][1] = *(const v8bf*)&sa[rb + (((q | 4) ^ f7) << 3)];
    }
  };
  auto readB = [&](const __bf16* sb, int hn) {
#pragma unroll
    for (int j = 0; j < 4; ++j) {
      const int rb = (hn * 128 + qc * 64 + j * 16 + fr) * 64;
      bfr[j][0] = *(const v8bf*)&sb[rb + ((q ^ f7) << 3)];
      bfr[j][1] = *(const v8bf*)&sb[rb + (((q | 4) ^ f7) << 3)];
    }
  };

  constexpr int NT = KD / 64;
  constexpr int NI = NT / 2;
  __bf16* s0 = lds;
  __bf16* s1 = lds + 32768;

  // prologue: tile0 all 4 halves + tile1 {B0,A1,B1}; tile1.A0 is JIT at ph1.
  stage(0, 0, 0); stage(0, 1, 0); stage(0, 0, 1); stage(0, 1, 1);
  stage(1, 1, 0); stage(1, 0, 1); stage(1, 1, 1);
  VMW(6); BAR;

#pragma unroll 1
  for (int m = 0; m < NI; ++m) {
    const bool nl = (m != NI - 1);
    const int t1 = 2 * m + 1, t2 = 2 * m + 2, t3 = 2 * m + 3;
    // ph1: reads s0.A0 -> af0, s0.B-half0 ; stage s1.A0 (t1, JIT)
    readA(s0, 0, af0); readB(s0 + 16384, 0);
    stage(t1, 0, 0);
    LGKM0; BAR; MM(af0, 0, 0);
    // ph2: reads s0.A1 -> af1 (bfr held); stage s0.B0 (t2)
    readA(s0, 1, af1);
    if (nl) stage(t2, 1, 0);
    LGKM0; BAR; MM(af1, 1, 0);
    // ph3: reads s0.B-half1 (af1 held); stage s0.A1 (t2)
    readB(s0 + 16384, 1);
    if (nl) stage(t2, 0, 1);
    LGKM0; BAR; MM(af1, 1, 1);
    // ph4: NO ds_reads (af0, bfr held); stage s0.B1 (t2); counted vmcnt
    if (nl) stage(t2, 1, 1);
    if (nl) { VMW(6); } else { VMW(0); }
    BAR; MM(af0, 0, 1);
    // ph5: reads s1.A0 -> af0, s1.B-half0 ; stage s0.A0 (t2)
    readA(s1, 0, af0); readB(s1 + 16384, 0);
    if (nl) stage(t2, 0, 0);
    LGKM0; BAR; MM(af0, 0, 0);
    // ph6: reads s1.A1 -> af1 ; stage s1.B0 (t3)
    readA(s1, 1, af1);
    if (nl) stage(t3, 1, 0);
    LGKM0; BAR; MM(af1, 1, 0);
    // ph7: reads s1.B-half1 ; stage s1.A1 (t3)
    readB(s1 + 16384, 1);
    if (nl) stage(t3, 0, 1);
    LGKM0; BAR; MM(af1, 1, 1);
    // ph8: NO ds_reads ; stage s1.B1 (t3); counted vmcnt
    if (nl) stage(t3, 1, 1);
    if (nl) { VMW(6); } else { VMW(0); }
    BAR; MM(af0, 0, 1);
  }

  // Output routing (EPI 0 merged K/Q): this block's 256 cols are entirely
  // in one half; pick output base, norm target, and column offset.
  OT* Ob = Obase;
  float* dkp = dk2;
  int coff = 0;
  if (EPI == 0 && n0 >= 1024) { Ob = Obase2; dkp = dk2b; coff = 1024; }
  OT* O = Ob + z * sO;

  // Epilogue. acc[ai][bj] reg r:
  //   row = m0 + (ai>>1)*128 + qr*32 + (ai&1)*16 + fr
  //   col = n0 + (bj>>2)*128 + qc*64 + (bj&3)*16 + q*4 + r  (r contiguous)
#pragma unroll
  for (int ai = 0; ai < 4; ++ai) {
    const int row = m0 + (ai >> 1) * 128 + qr * 32 + (ai & 1) * 16 + fr;
    float rk = 0.f, rs = 0.f;
    if (EPI == 1) rk = dk2[z * 2048 + row];
#pragma unroll
    for (int bj = 0; bj < 8; ++bj) {
      const int colb = n0 + (bj >> 2) * 128 + qc * 64 + (bj & 3) * 16 + q * 4;
      float cv[4];
      if (EPI == 0) {
        v4bf bb = *(const v4bf*)&bias[colb];
#pragma unroll
        for (int r = 0; r < 4; ++r) cv[r] = (float)bb[r];
      }
      if (EPI == 1 || EPI == 2) {
        v4f dd = *(const v4f*)&dq2[z * 2048 + colb];
#pragma unroll
        for (int r = 0; r < 4; ++r) cv[r] = dd[r];
      }
      float vv[4];
#pragma unroll
      for (int r = 0; r < 4; ++r) {
        float v = acc[ai][bj][r];
        if (EPI == 0) {
          v = fminf(fmaxf(v + cv[r], -32.f), 32.f);
          rs += v * v;
        }
        if (EPI == 1) {
          v *= rsqrtf(fmaxf(rk * cv[r], 1e-12f));
          v = fminf(fmaxf(v, -4.f), 4.f);
          v = __expf(v);
        }
        if (EPI == 2) {
          v = v / cv[r];
          v = fminf(fmaxf(v, -1.f), 1.f);
        }
        vv[r] = v;
      }
      if (sizeof(OT) == 2) {
        v4bf o;
#pragma unroll
        for (int r = 0; r < 4; ++r) o[r] = (__bf16)vv[r];
        if (EPI == 1) {
#pragma unroll
          for (int r = 0; r < 4; ++r) rs += (float)o[r];  // denom = sum of stored bf16
        }
        *(v4bf*)&O[(long)row * ldo + (colb - coff)] = o;
      } else {
        v4f o;
#pragma unroll
        for (int r = 0; r < 4; ++r) o[r] = vv[r];
        *(v4f*)&O[(long)row * ldo + (colb - coff)] = o;
      }
    }
    if (EPI == 0) {
      rs += __shfl_xor(rs, 16);
      rs += __shfl_xor(rs, 32);
      if (q == 0) atomicAdd(&dkp[z * 2048 + row], rs);
    }
    if (EPI == 1) {
      rs += __shfl_xor(rs, 16);
      rs += __shfl_xor(rs, 32);
      if (q == 0) atomicAdd(&snorm[z * 2048 + row], rs);
    }
  }
}

extern "C" void kernel_launch(void* const* d_in, const int* in_sizes, int n_in,
                              void* d_out, int out_size, void* d_ws, size_t ws_size,
                              hipStream_t stream) {
  const float* X    = (const float*)d_in[0];
  const float* Wk_w = (const float*)d_in[1];
  const float* Wk_b = (const float*)d_in[2];
  const float* Wq_w = (const float*)d_in[3];
  const float* Wq_b = (const float*)d_in[4];
  float* out = (float*)d_out;

  // ws: [0,32M): XT bf16 [n][b][c] -> later Xbf bf16 [n][c][b]
  //     [32M,96M): YT bf16 [n][k][b] (holds E=exp after GEMM-Y)
  //     [96M+): DK2, DQ2, SNORM, W (combined [2048][1024]), bb (combined bias)
  char* ws = (char*)d_ws;
  __bf16* XT  = (__bf16*)(ws);
  __bf16* Xbf = (__bf16*)(ws);
  __bf16* YT  = (__bf16*)(ws + 33554432L);
  char* aux   = ws + 100663296L;
  float*  DK2   = (float*)(aux);
  float*  DQ2   = (float*)(aux + 65536L);
  float*  SNORM = (float*)(aux + 131072L);
  __bf16* W     = (__bf16*)(aux + 196608L);               // 4 MiB
  __bf16* bb    = (__bf16*)(aux + 196608L + 4194304L);    // 4 KiB
  // d_out (64 MiB) holds KT|QT until GEMM3 overwrites it with Z.
  __bf16* KT = (__bf16*)d_out;
  __bf16* QT = (__bf16*)((char*)d_out + 33554432L);

  // 0) combined weight conversion (1 dispatch) + biases/zeroing (1 dispatch)
  cvt_weights<<<dim3(1024, 2), 256, 0, stream>>>(Wk_w, Wq_w, W);
  prep_small<<<1, 256, 0, stream>>>(Wk_b, Wq_b, bb, DK2);
  // 1) XT[n][b][c] = (bf16) X[n][c][b]
  cvt_transpose<<<dim3(32, 16, 8), 256, 0, stream>>>(X, XT);
  // 2) merged projection: [KT|QT][n][b][o] = XT[b,:]·W[o,:] + bb[o];
  //    fused rownorms -> DK2 (K half), DQ2 (Q half)
  gemm256<1024, 0, __bf16><<<dim3(8, 8, 8), 512, 0, stream>>>(
      XT, W, KT, QT, bb, DK2, DQ2, nullptr, nullptr,
      2048L * 1024, 0L, 2048L * 1024, 1024);
  // 3) Xbf = (bf16) X  (XT dead; same ws region)
  cvt_bf16<<<16384, 256, 0, stream>>>(X, Xbf, 16777216L);
  // 4) YT[n][k][b] = exp(clamp(cosine-score)); fused row-sum -> SNORM[n][k]
  gemm256<1024, 1, __bf16><<<dim3(8, 8, 8), 512, 0, stream>>>(
      KT, QT, YT, nullptr, nullptr, DK2, nullptr, DQ2, SNORM,
      2048L * 1024, 2048L * 1024, 2048L * 2048, 2048);
  // 5) Z[n][c][k] = (Xbf[c,:]·E[k,:]) / SNORM[k]  -> d_out fp32
  gemm256<2048, 2, float><<<dim3(8, 4, 8), 512, 0, stream>>>(
      Xbf, YT, out, nullptr, nullptr, nullptr, nullptr, SNORM, nullptr,
      1024L * 2048, 2048L * 2048, 1024L * 2048, 2048);
}

// Round 12
// 342.896 us; speedup vs baseline: 1.0625x; 1.0128x over previous
//
#include <hip/hip_runtime.h>
#include <hip/hip_bf16.h>

typedef __bf16 v8bf __attribute__((ext_vector_type(8)));
typedef __bf16 v4bf __attribute__((ext_vector_type(4)));
typedef float  v4f  __attribute__((ext_vector_type(4)));

#define AS1 __attribute__((address_space(1)))
#define AS3 __attribute__((address_space(3)))

static __device__ __forceinline__ void gload_lds16(const void* g, void* l) {
  __builtin_amdgcn_global_load_lds((const AS1 void*)g, (AS3 void*)l, 16, 0, 0);
}

// ---- combined Wk|Wq fp32 -> bf16 into W[2048][1024] (one dispatch) ----
__global__ __launch_bounds__(256)
void cvt_weights(const float* __restrict__ wk, const float* __restrict__ wq,
                 __bf16* __restrict__ W) {
  const float* src = blockIdx.y ? wq : wk;
  __bf16* dst = W + (long)blockIdx.y * 1048576L;
  const long i = ((long)blockIdx.x * 256 + threadIdx.x) * 4;
  v4f v = *(const v4f*)&src[i];
  v4bf o;
#pragma unroll
  for (int u = 0; u < 4; ++u) o[u] = (__bf16)v[u];
  *(v4bf*)&dst[i] = o;
}

// ---- biases -> bf16 + zero DK2|DQ2|SNORM, single block ----
__global__ __launch_bounds__(256)
void prep_small(const float* __restrict__ bk, const float* __restrict__ bq,
                __bf16* __restrict__ bb, float* __restrict__ zbuf) {
  const int tid = threadIdx.x;
  {
    v4f v = *(const v4f*)&bk[tid * 4];
    v4bf o;
#pragma unroll
    for (int u = 0; u < 4; ++u) o[u] = (__bf16)v[u];
    *(v4bf*)&bb[tid * 4] = o;
    v = *(const v4f*)&bq[tid * 4];
#pragma unroll
    for (int u = 0; u < 4; ++u) o[u] = (__bf16)v[u];
    *(v4bf*)&bb[1024 + tid * 4] = o;
  }
  // zero 49152 floats (DK2|DQ2|SNORM): 48 v4f per thread
#pragma unroll
  for (int it = 0; it < 48; ++it)
    *(v4f*)&zbuf[(it * 256 + tid) * 4] = v4f{0.f, 0.f, 0.f, 0.f};
}

// ---- X [n][c][b] fp32 -> XT [n][b][c] bf16, 64x64 tiles via LDS ----
__global__ __launch_bounds__(256)
void cvt_transpose(const float* __restrict__ X, __bf16* __restrict__ XT) {
  __shared__ float t[64][65];
  const int b0 = blockIdx.x * 64, c0 = blockIdx.y * 64;
  const long n = blockIdx.z;
  const float* Xp = X + n * (1024L * 2048);
  __bf16* Tp = XT + n * (2048L * 1024);
  const int tid = threadIdx.x;
  const int r16 = tid >> 4, c4 = (tid & 15) * 4;
#pragma unroll
  for (int it = 0; it < 4; ++it) {
    const int r = r16 + it * 16;   // local c
    *(v4f*)&t[r][c4] = *(const v4f*)&Xp[(long)(c0 + r) * 2048 + b0 + c4];
  }
  __syncthreads();
  const int rb8 = tid >> 3, c8 = (tid & 7) * 8;
#pragma unroll
  for (int it = 0; it < 2; ++it) {
    const int rb = rb8 + it * 32;  // local b
    v8bf o;
#pragma unroll
    for (int u = 0; u < 8; ++u) o[u] = (__bf16)t[c8 + u][rb];
    *(v8bf*)&Tp[(long)(b0 + rb) * 1024 + c0 + c8] = o;
  }
}

// ---- 256x256 TN GEMM, 8-phase (R6/R8-verified core), counted vmcnt ----
// 8 waves (4x2 qr/qc), BK=64, double-buffered LDS (128 KiB), XOR-swizzle
// (slot s of row r holds k-chunk s^(r&7); pre-swizzled global src, linear
// LDS dest; fr/q fragment read pattern = MEASURED 0 bank conflicts).
// Phase = [ds_reads][stage][lgkmcnt(0)][vmcnt(6) at ph4/8][BAR][setprio MFMA]
// A fragments held in af0/af1 across phases -> ph4/ph8 have no ds_reads
// (24 ds_read_b128 per K-tile/wave).
// Swapped mfma(B,A): acc reg-quad = 4 consecutive cols -> vector stores.
// EPI 0 (merged K/Q projection): B = combined W[2048][1024]; col tile is
//   entirely in K half (-> KT, dk2) or Q half (-> QT, dk2b). += bias,
//   clamp +-32; fused rownorm (atomic).
// EPI 1: *= rsqrt(max(dk2[row]*dq2[col],eps)), clamp +-4, store exp();
//        fused row-sum of bf16(exp) -> snorm[row] (atomic);
//        PLUS fused X->Xbf copy (XT region is dead during this GEMM;
//        GEMM3, the only Xbf reader, is stream-ordered after).
// EPI 2: /= dq2[col] (softmax denominator), clamp +-1.
#define BAR __builtin_amdgcn_s_barrier()
#define LGKM0 do { asm volatile("s_waitcnt lgkmcnt(0)" ::: "memory"); \
                   __builtin_amdgcn_sched_barrier(0); } while (0)
#define VMW(N) do { asm volatile("s_waitcnt vmcnt(" #N ")" ::: "memory"); \
                    __builtin_amdgcn_sched_barrier(0); } while (0)
#define MM(AF, HM, HN) do { \
  __builtin_amdgcn_s_setprio(1); \
  _Pragma("unroll") for (int ks = 0; ks < 2; ++ks) \
  _Pragma("unroll") for (int u = 0; u < 2; ++u) \
  _Pragma("unroll") for (int j = 0; j < 4; ++j) \
    acc[2 * (HM) + u][4 * (HN) + j] = __builtin_amdgcn_mfma_f32_16x16x32_bf16( \
        bfr[j][ks], AF[u][ks], acc[2 * (HM) + u][4 * (HN) + j], 0, 0, 0); \
  __builtin_amdgcn_s_setprio(0); } while (0)

template<int KD, int EPI, typename OT>
__global__ __launch_bounds__(512, 2)
void gemm256(const __bf16* __restrict__ Abase, const __bf16* __restrict__ Bbase,
             OT* __restrict__ Obase, OT* __restrict__ Obase2,
             const __bf16* __restrict__ bias,
             float* __restrict__ dk2, float* __restrict__ dk2b,
             const float* __restrict__ dq2, float* __restrict__ snorm,
             const float* __restrict__ xsrc, __bf16* __restrict__ xdst,
             long sA, long sB, long sO, int ldo) {
  // buf0 (even tiles): A[256][64] @0, B @16384; buf1 (odd tiles) @32768.
  __shared__ __align__(128) __bf16 lds[65536];

  const int tid = threadIdx.x;
  const int wave = tid >> 6, lane = tid & 63;
  const int qr = wave >> 1, qc = wave & 1;   // 4x2 wave grid
  const int fr = lane & 15, q = lane >> 4;
  const int f7 = fr & 7;

  // XCD-chunked bijective swizzle (nwg divisible by 8)
  const int gx = gridDim.x, gy = gridDim.y;
  int id = blockIdx.x + gx * (blockIdx.y + gy * blockIdx.z);
  const int chunk8 = (gx * gy * gridDim.z) >> 3;
  id = (id & 7) * chunk8 + (id >> 3);
  const int bx = id % gx;
  const int rem = id / gx;
  const int by = rem % gy;
  const long z = rem / gy;

  const int n0 = bx * 256, m0 = by * 256;
  const __bf16* A = Abase + z * sA + (long)m0 * KD;
  const __bf16* B = Bbase + z * sB + (long)n0 * KD;

  // staging: wave w, instr i covers rows [half*128+w*16+i*8, +8);
  // lane l -> row +(l>>3), slot (l&7) holds k-chunk ((l&7)^(l>>3)).
  const int lrow = wave * 16 + (lane >> 3);
  const int lchunk = ((lane & 7) ^ (lane >> 3)) << 3;
  const __bf16* Alane = A + (long)lrow * KD + lchunk;
  const __bf16* Blane = B + (long)lrow * KD + lchunk;
  const int dbase = wave * 1024;

  auto stage = [&](int kt, int isB, int half) {
    const __bf16* gp = (isB ? Blane : Alane) + (long)(half * 128) * KD + kt * 64;
    __bf16* dp = lds + (kt & 1) * 32768 + isB * 16384 + half * 8192 + dbase;
    gload_lds16(gp, dp);
    gload_lds16(gp + (long)8 * KD, dp + 512);
  };

  v4f acc[4][8];
#pragma unroll
  for (int i = 0; i < 4; ++i)
#pragma unroll
    for (int j = 0; j < 8; ++j) acc[i][j] = {0.f, 0.f, 0.f, 0.f};

  v8bf af0[2][2], af1[2][2], bfr[4][2];
  auto readA = [&](const __bf16* sa, int hm, v8bf (&dst)[2][2]) {
#pragma unroll
    for (int u = 0; u < 2; ++u) {
      const int rb = (hm * 128 + qr * 32 + u * 16 + fr) * 64;
      dst[u][0] = *(const v8bf*)&sa[rb + ((q ^ f7) << 3)];
      dst[u][1] = *(const v8bf*)&sa[rb + (((q | 4) ^ f7) << 3)];
    }
  };
  auto readB = [&](const __bf16* sb, int hn) {
#pragma unroll
    for (int j = 0; j < 4; ++j) {
      const int rb = (hn * 128 + qc * 64 + j * 16 + fr) * 64;
      bfr[j][0] = *(const v8bf*)&sb[rb + ((q ^ f7) << 3)];
      bfr[j][1] = *(const v8bf*)&sb[rb + (((q | 4) ^ f7) << 3)];
    }
  };

  constexpr int NT = KD / 64;
  constexpr int NI = NT / 2;
  __bf16* s0 = lds;
  __bf16* s1 = lds + 32768;

  // prologue: tile0 all 4 halves + tile1 {B0,A1,B1}; tile1.A0 is JIT at ph1.
  stage(0, 0, 0); stage(0, 1, 0); stage(0, 0, 1); stage(0, 1, 1);
  stage(1, 1, 0); stage(1, 0, 1); stage(1, 1, 1);
  VMW(6); BAR;

#pragma unroll 1
  for (int m = 0; m < NI; ++m) {
    const bool nl = (m != NI - 1);
    const int t1 = 2 * m + 1, t2 = 2 * m + 2, t3 = 2 * m + 3;
    // ph1: reads s0.A0 -> af0, s0.B-half0 ; stage s1.A0 (t1, JIT)
    readA(s0, 0, af0); readB(s0 + 16384, 0);
    stage(t1, 0, 0);
    LGKM0; BAR; MM(af0, 0, 0);
    // ph2: reads s0.A1 -> af1 (bfr held); stage s0.B0 (t2)
    readA(s0, 1, af1);
    if (nl) stage(t2, 1, 0);
    LGKM0; BAR; MM(af1, 1, 0);
    // ph3: reads s0.B-half1 (af1 held); stage s0.A1 (t2)
    readB(s0 + 16384, 1);
    if (nl) stage(t2, 0, 1);
    LGKM0; BAR; MM(af1, 1, 1);
    // ph4: NO ds_reads (af0, bfr held); stage s0.B1 (t2); counted vmcnt
    if (nl) stage(t2, 1, 1);
    if (nl) { VMW(6); } else { VMW(0); }
    BAR; MM(af0, 0, 1);
    // ph5: reads s1.A0 -> af0, s1.B-half0 ; stage s0.A0 (t2)
    readA(s1, 0, af0); readB(s1 + 16384, 0);
    if (nl) stage(t2, 0, 0);
    LGKM0; BAR; MM(af0, 0, 0);
    // ph6: reads s1.A1 -> af1 ; stage s1.B0 (t3)
    readA(s1, 1, af1);
    if (nl) stage(t3, 1, 0);
    LGKM0; BAR; MM(af1, 1, 0);
    // ph7: reads s1.B-half1 ; stage s1.A1 (t3)
    readB(s1 + 16384, 1);
    if (nl) stage(t3, 0, 1);
    LGKM0; BAR; MM(af1, 1, 1);
    // ph8: NO ds_reads ; stage s1.B1 (t3); counted vmcnt
    if (nl) stage(t3, 1, 1);
    if (nl) { VMW(6); } else { VMW(0); }
    BAR; MM(af0, 0, 1);
  }

  // Output routing (EPI 0 merged K/Q): this block's 256 cols are entirely
  // in one half; pick output base, norm target, and column offset.
  OT* Ob = Obase;
  float* dkp = dk2;
  int coff = 0;
  if (EPI == 0 && n0 >= 1024) { Ob = Obase2; dkp = dk2b; coff = 1024; }
  OT* O = Ob + z * sO;

  // Epilogue. acc[ai][bj] reg r:
  //   row = m0 + (ai>>1)*128 + qr*32 + (ai&1)*16 + fr
  //   col = n0 + (bj>>2)*128 + qc*64 + (bj&3)*16 + q*4 + r  (r contiguous)
#pragma unroll
  for (int ai = 0; ai < 4; ++ai) {
    const int row = m0 + (ai >> 1) * 128 + qr * 32 + (ai & 1) * 16 + fr;
    float rk = 0.f, rs = 0.f;
    if (EPI == 1) rk = dk2[z * 2048 + row];
#pragma unroll
    for (int bj = 0; bj < 8; ++bj) {
      const int colb = n0 + (bj >> 2) * 128 + qc * 64 + (bj & 3) * 16 + q * 4;
      float cv[4];
      if (EPI == 0) {
        v4bf bb = *(const v4bf*)&bias[colb];
#pragma unroll
        for (int r = 0; r < 4; ++r) cv[r] = (float)bb[r];
      }
      if (EPI == 1 || EPI == 2) {
        v4f dd = *(const v4f*)&dq2[z * 2048 + colb];
#pragma unroll
        for (int r = 0; r < 4; ++r) cv[r] = dd[r];
      }
      float vv[4];
#pragma unroll
      for (int r = 0; r < 4; ++r) {
        float v = acc[ai][bj][r];
        if (EPI == 0) {
          v = fminf(fmaxf(v + cv[r], -32.f), 32.f);
          rs += v * v;
        }
        if (EPI == 1) {
          v *= rsqrtf(fmaxf(rk * cv[r], 1e-12f));
          v = fminf(fmaxf(v, -4.f), 4.f);
          v = __expf(v);
        }
        if (EPI == 2) {
          v = v / cv[r];
          v = fminf(fmaxf(v, -1.f), 1.f);
        }
        vv[r] = v;
      }
      if (sizeof(OT) == 2) {
        v4bf o;
#pragma unroll
        for (int r = 0; r < 4; ++r) o[r] = (__bf16)vv[r];
        if (EPI == 1) {
#pragma unroll
          for (int r = 0; r < 4; ++r) rs += (float)o[r];  // denom = sum of stored bf16
        }
        *(v4bf*)&O[(long)row * ldo + (colb - coff)] = o;
      } else {
        v4f o;
#pragma unroll
        for (int r = 0; r < 4; ++r) o[r] = vv[r];
        *(v4f*)&O[(long)row * ldo + (colb - coff)] = o;
      }
    }
    if (EPI == 0) {
      rs += __shfl_xor(rs, 16);
      rs += __shfl_xor(rs, 32);
      if (q == 0) atomicAdd(&dkp[z * 2048 + row], rs);
    }
    if (EPI == 1) {
      rs += __shfl_xor(rs, 16);
      rs += __shfl_xor(rs, 32);
      if (q == 0) atomicAdd(&snorm[z * 2048 + row], rs);
    }
  }

  // EPI 1 only: fused X -> Xbf copy. Each of the 512 blocks copies its
  // 32768-float slice (coalesced v4 loads/stores; overlaps other blocks'
  // GEMM work via stagger; XT region is dead during this dispatch).
  if (EPI == 1) {
    const long base = (long)id * 32768 + tid * 4;
#pragma unroll
    for (int it = 0; it < 16; ++it) {
      v4f v = *(const v4f*)&xsrc[base + it * 2048];
      v4bf o;
#pragma unroll
      for (int u = 0; u < 4; ++u) o[u] = (__bf16)v[u];
      *(v4bf*)&xdst[base + it * 2048] = o;
    }
  }
}

extern "C" void kernel_launch(void* const* d_in, const int* in_sizes, int n_in,
                              void* d_out, int out_size, void* d_ws, size_t ws_size,
                              hipStream_t stream) {
  const float* X    = (const float*)d_in[0];
  const float* Wk_w = (const float*)d_in[1];
  const float* Wk_b = (const float*)d_in[2];
  const float* Wq_w = (const float*)d_in[3];
  const float* Wq_b = (const float*)d_in[4];
  float* out = (float*)d_out;

  // ws: [0,32M): XT bf16 [n][b][c] -> later Xbf bf16 [n][c][b]
  //     [32M,96M): YT bf16 [n][k][b] (holds E=exp after GEMM-Y)
  //     [96M+): DK2, DQ2, SNORM, W (combined [2048][1024]), bb (combined bias)
  char* ws = (char*)d_ws;
  __bf16* XT  = (__bf16*)(ws);
  __bf16* Xbf = (__bf16*)(ws);
  __bf16* YT  = (__bf16*)(ws + 33554432L);
  char* aux   = ws + 100663296L;
  float*  DK2   = (float*)(aux);
  float*  DQ2   = (float*)(aux + 65536L);
  float*  SNORM = (float*)(aux + 131072L);
  __bf16* W     = (__bf16*)(aux + 196608L);               // 4 MiB
  __bf16* bb    = (__bf16*)(aux + 196608L + 4194304L);    // 4 KiB
  // d_out (64 MiB) holds KT|QT until GEMM3 overwrites it with Z.
  __bf16* KT = (__bf16*)d_out;
  __bf16* QT = (__bf16*)((char*)d_out + 33554432L);

  // 0) combined weight conversion (1 dispatch) + biases/zeroing (1 dispatch)
  cvt_weights<<<dim3(1024, 2), 256, 0, stream>>>(Wk_w, Wq_w, W);
  prep_small<<<1, 256, 0, stream>>>(Wk_b, Wq_b, bb, DK2);
  // 1) XT[n][b][c] = (bf16) X[n][c][b]
  cvt_transpose<<<dim3(32, 16, 8), 256, 0, stream>>>(X, XT);
  // 2) merged projection: [KT|QT][n][b][o] = XT[b,:]·W[o,:] + bb[o];
  //    fused rownorms -> DK2 (K half), DQ2 (Q half)
  gemm256<1024, 0, __bf16><<<dim3(8, 8, 8), 512, 0, stream>>>(
      XT, W, KT, QT, bb, DK2, DQ2, nullptr, nullptr, nullptr, nullptr,
      2048L * 1024, 0L, 2048L * 1024, 1024);
  // 3) YT[n][k][b] = exp(clamp(cosine-score)); fused row-sum -> SNORM[n][k];
  //    fused X -> Xbf copy (XT dead from here; Xbf shares its region)
  gemm256<1024, 1, __bf16><<<dim3(8, 8, 8), 512, 0, stream>>>(
      KT, QT, YT, nullptr, nullptr, DK2, nullptr, DQ2, SNORM, X, Xbf,
      2048L * 1024, 2048L * 1024, 2048L * 2048, 2048);
  // 4) Z[n][c][k] = (Xbf[c,:]·E[k,:]) / SNORM[k]  -> d_out fp32
  gemm256<2048, 2, float><<<dim3(8, 4, 8), 512, 0, stream>>>(
      Xbf, YT, out, nullptr, nullptr, nullptr, nullptr, SNORM, nullptr,
      nullptr, nullptr, 1024L * 2048, 2048L * 2048, 1024L * 2048, 2048);
}

// Round 13
// 327.470 us; speedup vs baseline: 1.1125x; 1.0471x over previous
//
#include <hip/hip_runtime.h>
#include <hip/hip_bf16.h>

typedef __bf16 v8bf __attribute__((ext_vector_type(8)));
typedef __bf16 v4bf __attribute__((ext_vector_type(4)));
typedef float  v4f  __attribute__((ext_vector_type(4)));

#define AS1 __attribute__((address_space(1)))
#define AS3 __attribute__((address_space(3)))

static __device__ __forceinline__ void gload_lds16(const void* g, void* l) {
  __builtin_amdgcn_global_load_lds((const AS1 void*)g, (AS3 void*)l, 16, 0, 0);
}

// ---- combined Wk|Wq fp32 -> bf16 into W[2048][1024] (one dispatch) ----
__global__ __launch_bounds__(256)
void cvt_weights(const float* __restrict__ wk, const float* __restrict__ wq,
                 __bf16* __restrict__ W) {
  const float* src = blockIdx.y ? wq : wk;
  __bf16* dst = W + (long)blockIdx.y * 1048576L;
  const long i = ((long)blockIdx.x * 256 + threadIdx.x) * 4;
  v4f v = *(const v4f*)&src[i];
  v4bf o;
#pragma unroll
  for (int u = 0; u < 4; ++u) o[u] = (__bf16)v[u];
  *(v4bf*)&dst[i] = o;
}

// ---- biases -> bf16 + zero DK2|DQ2|SNORM, single block ----
__global__ __launch_bounds__(256)
void prep_small(const float* __restrict__ bk, const float* __restrict__ bq,
                __bf16* __restrict__ bb, float* __restrict__ zbuf) {
  const int tid = threadIdx.x;
  {
    v4f v = *(const v4f*)&bk[tid * 4];
    v4bf o;
#pragma unroll
    for (int u = 0; u < 4; ++u) o[u] = (__bf16)v[u];
    *(v4bf*)&bb[tid * 4] = o;
    v = *(const v4f*)&bq[tid * 4];
#pragma unroll
    for (int u = 0; u < 4; ++u) o[u] = (__bf16)v[u];
    *(v4bf*)&bb[1024 + tid * 4] = o;
  }
  // zero 49152 floats (DK2|DQ2|SNORM): 48 v4f per thread
#pragma unroll
  for (int it = 0; it < 48; ++it)
    *(v4f*)&zbuf[(it * 256 + tid) * 4] = v4f{0.f, 0.f, 0.f, 0.f};
}

// ---- X [n][c][b] fp32 -> XT [n][b][c] bf16 (transposed) AND
//      Xbf [n][c][b] bf16 (straight copy) in one pass over X ----
__global__ __launch_bounds__(256)
void cvt_transpose(const float* __restrict__ X, __bf16* __restrict__ XT,
                   __bf16* __restrict__ Xbf) {
  __shared__ float t[64][65];
  const int b0 = blockIdx.x * 64, c0 = blockIdx.y * 64;
  const long n = blockIdx.z;
  const float* Xp = X + n * (1024L * 2048);
  __bf16* Tp = XT + n * (2048L * 1024);
  __bf16* Cp = Xbf + n * (1024L * 2048);
  const int tid = threadIdx.x;
  const int r16 = tid >> 4, c4 = (tid & 15) * 4;
#pragma unroll
  for (int it = 0; it < 4; ++it) {
    const int r = r16 + it * 16;   // local c
    v4f v = *(const v4f*)&Xp[(long)(c0 + r) * 2048 + b0 + c4];
    *(v4f*)&t[r][c4] = v;
    v4bf o;
#pragma unroll
    for (int u = 0; u < 4; ++u) o[u] = (__bf16)v[u];
    *(v4bf*)&Cp[(long)(c0 + r) * 2048 + b0 + c4] = o;  // straight bf16 copy
  }
  __syncthreads();
  const int rb8 = tid >> 3, c8 = (tid & 7) * 8;
#pragma unroll
  for (int it = 0; it < 2; ++it) {
    const int rb = rb8 + it * 32;  // local b
    v8bf o;
#pragma unroll
    for (int u = 0; u < 8; ++u) o[u] = (__bf16)t[c8 + u][rb];
    *(v8bf*)&Tp[(long)(b0 + rb) * 1024 + c0 + c8] = o;
  }
}

// ---- 256x256 TN GEMM, 8-phase (R6/R8-verified core), counted vmcnt ----
// 8 waves (4x2 qr/qc), BK=64, double-buffered LDS (128 KiB), XOR-swizzle
// (slot s of row r holds k-chunk s^(r&7); pre-swizzled global src, linear
// LDS dest; fr/q fragment read pattern = MEASURED 0 bank conflicts).
// Phase = [ds_reads][stage][lgkmcnt(0)][vmcnt(6) at ph4/8][BAR][setprio MFMA]
// A fragments held in af0/af1 across phases -> ph4/ph8 have no ds_reads
// (24 ds_read_b128 per K-tile/wave).
// Swapped mfma(B,A): acc reg-quad = 4 consecutive cols -> vector stores.
// EPI 0 (merged K/Q projection): B = combined W[2048][1024]; col tile is
//   entirely in K half (-> KT, dk2) or Q half (-> QT, dk2b). += bias,
//   clamp +-32; fused rownorm (atomic).
// EPI 1: *= rsqrt(max(dk2[row]*dq2[col],eps)), clamp +-4, store exp();
//        fused row-sum of bf16(exp) -> snorm[row] (atomic)
// EPI 2: /= dq2[col] (softmax denominator), clamp +-1.
#define BAR __builtin_amdgcn_s_barrier()
#define LGKM0 do { asm volatile("s_waitcnt lgkmcnt(0)" ::: "memory"); \
                   __builtin_amdgcn_sched_barrier(0); } while (0)
#define VMW(N) do { asm volatile("s_waitcnt vmcnt(" #N ")" ::: "memory"); \
                    __builtin_amdgcn_sched_barrier(0); } while (0)
#define MM(AF, HM, HN) do { \
  __builtin_amdgcn_s_setprio(1); \
  _Pragma("unroll") for (int ks = 0; ks < 2; ++ks) \
  _Pragma("unroll") for (int u = 0; u < 2; ++u) \
  _Pragma("unroll") for (int j = 0; j < 4; ++j) \
    acc[2 * (HM) + u][4 * (HN) + j] = __builtin_amdgcn_mfma_f32_16x16x32_bf16( \
        bfr[j][ks], AF[u][ks], acc[2 * (HM) + u][4 * (HN) + j], 0, 0, 0); \
  __builtin_amdgcn_s_setprio(0); } while (0)

template<int KD, int EPI, typename OT>
__global__ __launch_bounds__(512, 2)
void gemm256(const __bf16* __restrict__ Abase, const __bf16* __restrict__ Bbase,
             OT* __restrict__ Obase, OT* __restrict__ Obase2,
             const __bf16* __restrict__ bias,
             float* __restrict__ dk2, float* __restrict__ dk2b,
             const float* __restrict__ dq2, float* __restrict__ snorm,
             long sA, long sB, long sO, int ldo) {
  // buf0 (even tiles): A[256][64] @0, B @16384; buf1 (odd tiles) @32768.
  __shared__ __align__(128) __bf16 lds[65536];

  const int tid = threadIdx.x;
  const int wave = tid >> 6, lane = tid & 63;
  const int qr = wave >> 1, qc = wave & 1;   // 4x2 wave grid
  const int fr = lane & 15, q = lane >> 4;
  const int f7 = fr & 7;

  // XCD-chunked bijective swizzle (nwg divisible by 8)
  const int gx = gridDim.x, gy = gridDim.y;
  int id = blockIdx.x + gx * (blockIdx.y + gy * blockIdx.z);
  const int chunk8 = (gx * gy * gridDim.z) >> 3;
  id = (id & 7) * chunk8 + (id >> 3);
  const int bx = id % gx;
  const int rem = id / gx;
  const int by = rem % gy;
  const long z = rem / gy;

  const int n0 = bx * 256, m0 = by * 256;
  const __bf16* A = Abase + z * sA + (long)m0 * KD;
  const __bf16* B = Bbase + z * sB + (long)n0 * KD;

  // staging: wave w, instr i covers rows [half*128+w*16+i*8, +8);
  // lane l -> row +(l>>3), slot (l&7) holds k-chunk ((l&7)^(l>>3)).
  const int lrow = wave * 16 + (lane >> 3);
  const int lchunk = ((lane & 7) ^ (lane >> 3)) << 3;
  const __bf16* Alane = A + (long)lrow * KD + lchunk;
  const __bf16* Blane = B + (long)lrow * KD + lchunk;
  const int dbase = wave * 1024;

  auto stage = [&](int kt, int isB, int half) {
    const __bf16* gp = (isB ? Blane : Alane) + (long)(half * 128) * KD + kt * 64;
    __bf16* dp = lds + (kt & 1) * 32768 + isB * 16384 + half * 8192 + dbase;
    gload_lds16(gp, dp);
    gload_lds16(gp + (long)8 * KD, dp + 512);
  };

  v4f acc[4][8];
#pragma unroll
  for (int i = 0; i < 4; ++i)
#pragma unroll
    for (int j = 0; j < 8; ++j) acc[i][j] = {0.f, 0.f, 0.f, 0.f};

  v8bf af0[2][2], af1[2][2], bfr[4][2];
  auto readA = [&](const __bf16* sa, int hm, v8bf (&dst)[2][2]) {
#pragma unroll
    for (int u = 0; u < 2; ++u) {
      const int rb = (hm * 128 + qr * 32 + u * 16 + fr) * 64;
      dst[u][0] = *(const v8bf*)&sa[rb + ((q ^ f7) << 3)];
      dst[u][1] = *(const v8bf*)&sa[rb + (((q | 4) ^ f7) << 3)];
    }
  };
  auto readB = [&](const __bf16* sb, int hn) {
#pragma unroll
    for (int j = 0; j < 4; ++j) {
      const int rb = (hn * 128 + qc * 64 + j * 16 + fr) * 64;
      bfr[j][0] = *(const v8bf*)&sb[rb + ((q ^ f7) << 3)];
      bfr[j][1] = *(const v8bf*)&sb[rb + (((q | 4) ^ f7) << 3)];
    }
  };

  constexpr int NT = KD / 64;
  constexpr int NI = NT / 2;
  __bf16* s0 = lds;
  __bf16* s1 = lds + 32768;

  // prologue: tile0 all 4 halves + tile1 {B0,A1,B1}; tile1.A0 is JIT at ph1.
  stage(0, 0, 0); stage(0, 1, 0); stage(0, 0, 1); stage(0, 1, 1);
  stage(1, 1, 0); stage(1, 0, 1); stage(1, 1, 1);
  VMW(6); BAR;

#pragma unroll 1
  for (int m = 0; m < NI; ++m) {
    const bool nl = (m != NI - 1);
    const int t1 = 2 * m + 1, t2 = 2 * m + 2, t3 = 2 * m + 3;
    // ph1: reads s0.A0 -> af0, s0.B-half0 ; stage s1.A0 (t1, JIT)
    readA(s0, 0, af0); readB(s0 + 16384, 0);
    stage(t1, 0, 0);
    LGKM0; BAR; MM(af0, 0, 0);
    // ph2: reads s0.A1 -> af1 (bfr held); stage s0.B0 (t2)
    readA(s0, 1, af1);
    if (nl) stage(t2, 1, 0);
    LGKM0; BAR; MM(af1, 1, 0);
    // ph3: reads s0.B-half1 (af1 held); stage s0.A1 (t2)
    readB(s0 + 16384, 1);
    if (nl) stage(t2, 0, 1);
    LGKM0; BAR; MM(af1, 1, 1);
    // ph4: NO ds_reads (af0, bfr held); stage s0.B1 (t2); counted vmcnt
    if (nl) stage(t2, 1, 1);
    if (nl) { VMW(6); } else { VMW(0); }
    BAR; MM(af0, 0, 1);
    // ph5: reads s1.A0 -> af0, s1.B-half0 ; stage s0.A0 (t2)
    readA(s1, 0, af0); readB(s1 + 16384, 0);
    if (nl) stage(t2, 0, 0);
    LGKM0; BAR; MM(af0, 0, 0);
    // ph6: reads s1.A1 -> af1 ; stage s1.B0 (t3)
    readA(s1, 1, af1);
    if (nl) stage(t3, 1, 0);
    LGKM0; BAR; MM(af1, 1, 0);
    // ph7: reads s1.B-half1 ; stage s1.A1 (t3)
    readB(s1 + 16384, 1);
    if (nl) stage(t3, 0, 1);
    LGKM0; BAR; MM(af1, 1, 1);
    // ph8: NO ds_reads ; stage s1.B1 (t3); counted vmcnt
    if (nl) stage(t3, 1, 1);
    if (nl) { VMW(6); } else { VMW(0); }
    BAR; MM(af0, 0, 1);
  }

  // Output routing (EPI 0 merged K/Q): this block's 256 cols are entirely
  // in one half; pick output base, norm target, and column offset.
  OT* Ob = Obase;
  float* dkp = dk2;
  int coff = 0;
  if (EPI == 0 && n0 >= 1024) { Ob = Obase2; dkp = dk2b; coff = 1024; }
  OT* O = Ob + z * sO;

  // Epilogue. acc[ai][bj] reg r:
  //   row = m0 + (ai>>1)*128 + qr*32 + (ai&1)*16 + fr
  //   col = n0 + (bj>>2)*128 + qc*64 + (bj&3)*16 + q*4 + r  (r contiguous)
#pragma unroll
  for (int ai = 0; ai < 4; ++ai) {
    const int row = m0 + (ai >> 1) * 128 + qr * 32 + (ai & 1) * 16 + fr;
    float rk = 0.f, rs = 0.f;
    if (EPI == 1) rk = dk2[z * 2048 + row];
#pragma unroll
    for (int bj = 0; bj < 8; ++bj) {
      const int colb = n0 + (bj >> 2) * 128 + qc * 64 + (bj & 3) * 16 + q * 4;
      float cv[4];
      if (EPI == 0) {
        v4bf bb = *(const v4bf*)&bias[colb];
#pragma unroll
        for (int r = 0; r < 4; ++r) cv[r] = (float)bb[r];
      }
      if (EPI == 1 || EPI == 2) {
        v4f dd = *(const v4f*)&dq2[z * 2048 + colb];
#pragma unroll
        for (int r = 0; r < 4; ++r) cv[r] = dd[r];
      }
      float vv[4];
#pragma unroll
      for (int r = 0; r < 4; ++r) {
        float v = acc[ai][bj][r];
        if (EPI == 0) {
          v = fminf(fmaxf(v + cv[r], -32.f), 32.f);
          rs += v * v;
        }
        if (EPI == 1) {
          v *= rsqrtf(fmaxf(rk * cv[r], 1e-12f));
          v = fminf(fmaxf(v, -4.f), 4.f);
          v = __expf(v);
        }
        if (EPI == 2) {
          v = v / cv[r];
          v = fminf(fmaxf(v, -1.f), 1.f);
        }
        vv[r] = v;
      }
      if (sizeof(OT) == 2) {
        v4bf o;
#pragma unroll
        for (int r = 0; r < 4; ++r) o[r] = (__bf16)vv[r];
        if (EPI == 1) {
#pragma unroll
          for (int r = 0; r < 4; ++r) rs += (float)o[r];  // denom = sum of stored bf16
        }
        *(v4bf*)&O[(long)row * ldo + (colb - coff)] = o;
      } else {
        v4f o;
#pragma unroll
        for (int r = 0; r < 4; ++r) o[r] = vv[r];
        *(v4f*)&O[(long)row * ldo + (colb - coff)] = o;
      }
    }
    if (EPI == 0) {
      rs += __shfl_xor(rs, 16);
      rs += __shfl_xor(rs, 32);
      if (q == 0) atomicAdd(&dkp[z * 2048 + row], rs);
    }
    if (EPI == 1) {
      rs += __shfl_xor(rs, 16);
      rs += __shfl_xor(rs, 32);
      if (q == 0) atomicAdd(&snorm[z * 2048 + row], rs);
    }
  }
}

extern "C" void kernel_launch(void* const* d_in, const int* in_sizes, int n_in,
                              void* d_out, int out_size, void* d_ws, size_t ws_size,
                              hipStream_t stream) {
  const float* X    = (const float*)d_in[0];
  const float* Wk_w = (const float*)d_in[1];
  const float* Wk_b = (const float*)d_in[2];
  const float* Wq_w = (const float*)d_in[3];
  const float* Wq_b = (const float*)d_in[4];
  float* out = (float*)d_out;

  // ws: [0,32M): Xbf bf16 [n][c][b]   (written by cvt_transpose, read GEMM3)
  //     [32M,64M): XT bf16 [n][b][c]  (dead after KQ-GEMM; YT overwrites)
  //     [32M,96M): YT bf16 [n][k][b]  (born at Y-GEMM)
  //     [96M+): DK2, DQ2, SNORM, W (combined [2048][1024]), bb (combined bias)
  char* ws = (char*)d_ws;
  __bf16* Xbf = (__bf16*)(ws);
  __bf16* XT  = (__bf16*)(ws + 33554432L);
  __bf16* YT  = (__bf16*)(ws + 33554432L);
  char* aux   = ws + 100663296L;
  float*  DK2   = (float*)(aux);
  float*  DQ2   = (float*)(aux + 65536L);
  float*  SNORM = (float*)(aux + 131072L);
  __bf16* W     = (__bf16*)(aux + 196608L);               // 4 MiB
  __bf16* bb    = (__bf16*)(aux + 196608L + 4194304L);    // 4 KiB
  // d_out (64 MiB) holds KT|QT until GEMM3 overwrites it with Z.
  __bf16* KT = (__bf16*)d_out;
  __bf16* QT = (__bf16*)((char*)d_out + 33554432L);

  // 0) combined weight conversion (1 dispatch) + biases/zeroing (1 dispatch)
  cvt_weights<<<dim3(1024, 2), 256, 0, stream>>>(Wk_w, Wq_w, W);
  prep_small<<<1, 256, 0, stream>>>(Wk_b, Wq_b, bb, DK2);
  // 1) one pass over X: XT[n][b][c] (transposed) + Xbf[n][c][b] (copy)
  cvt_transpose<<<dim3(32, 16, 8), 256, 0, stream>>>(X, XT, Xbf);
  // 2) merged projection: [KT|QT][n][b][o] = XT[b,:]·W[o,:] + bb[o];
  //    fused rownorms -> DK2 (K half), DQ2 (Q half)
  gemm256<1024, 0, __bf16><<<dim3(8, 8, 8), 512, 0, stream>>>(
      XT, W, KT, QT, bb, DK2, DQ2, nullptr, nullptr,
      2048L * 1024, 0L, 2048L * 1024, 1024);
  // 3) YT[n][k][b] = exp(clamp(cosine-score)); fused row-sum -> SNORM[n][k]
  //    (YT overwrites the dead XT region)
  gemm256<1024, 1, __bf16><<<dim3(8, 8, 8), 512, 0, stream>>>(
      KT, QT, YT, nullptr, nullptr, DK2, nullptr, DQ2, SNORM,
      2048L * 1024, 2048L * 1024, 2048L * 2048, 2048);
  // 4) Z[n][c][k] = (Xbf[c,:]·E[k,:]) / SNORM[k]  -> d_out fp32
  gemm256<2048, 2, float><<<dim3(8, 4, 8), 512, 0, stream>>>(
      Xbf, YT, out, nullptr, nullptr, nullptr, nullptr, SNORM, nullptr,
      1024L * 2048, 2048L * 2048, 1024L * 2048, 2048);
}